// Round 1
// baseline (6447.106 us; speedup 1.0000x reference)
//
#include <hip/hip_runtime.h>
#include <hip/hip_cooperative_groups.h>

namespace cg = cooperative_groups;

typedef __bf16 bf16;
typedef __bf16 bf16x8 __attribute__((ext_vector_type(8)));
typedef __bf16 bf16x4 __attribute__((ext_vector_type(4)));
typedef float  f32x4  __attribute__((ext_vector_type(4)));

// async global->LDS, 16B per lane. LDS dest must be lane-linear within the wave.
__device__ __forceinline__ void async16(const bf16* g, bf16* l) {
  __builtin_amdgcn_global_load_lds(
      (__attribute__((address_space(1))) void*)(void*)(const_cast<bf16*>(g)),
      (__attribute__((address_space(3))) void*)(void*)l,
      16, 0, 0);
}

// ---------------- elementwise converts / transposes / gathers ----------------

__global__ void cvt_bf16(const float* __restrict__ s, bf16* __restrict__ d, int n) {
  int i = blockIdx.x * blockDim.x + threadIdx.x;
  int stride = gridDim.x * blockDim.x;
  for (int k = i; k < n; k += stride) d[k] = (bf16)s[k];
}

// dst[c, r] = src[r, c]; src is R x C f32 (row-major), dst is C x R bf16.
__global__ void transpose_to_bf16(const float* __restrict__ src, bf16* __restrict__ dst,
                                  int R, int C) {
  __shared__ float tile[32][33];
  int c0 = blockIdx.x * 32, r0 = blockIdx.y * 32;
  int tx = threadIdx.x, ty = threadIdx.y;
#pragma unroll
  for (int k = 0; k < 32; k += 8)
    tile[ty + k][tx] = src[(size_t)(r0 + ty + k) * C + (c0 + tx)];
  __syncthreads();
#pragma unroll
  for (int k = 0; k < 32; k += 8)
    dst[(size_t)(c0 + ty + k) * R + (r0 + tx)] = (bf16)tile[tx][ty + k];
}

// X[r = t*64+b, :] = bf16(emb[tokens[b,t], :]), rows >= 3008 zeroed (M padded to 3072)
__global__ void gather_emb(const int* __restrict__ tokens, const float* __restrict__ emb,
                           bf16* __restrict__ X) {
  int r = blockIdx.x;
  int tid = threadIdx.x;
  if (r < 3008) {
    int t = r >> 6, b = r & 63;
    int tok = tokens[b * 47 + t];
    const float* e = emb + (size_t)tok * 512;
    for (int k = tid; k < 512; k += 128) X[(size_t)r * 512 + k] = (bf16)e[k];
  } else {
    for (int k = tid; k < 512; k += 128) X[(size_t)r * 512 + k] = (bf16)0.f;
  }
}

// S0[b, 0:1024] = bf16(enc_h), S0[b, 1024:2048] = 0
__global__ void init_state(const float* __restrict__ enc_h, bf16* __restrict__ S0) {
  int i = blockIdx.x * 256 + threadIdx.x;   // 0..65535
  int b = i >> 10, u = i & 1023;
  S0[(size_t)b * 2048 + u]        = (bf16)enc_h[i];
  S0[(size_t)b * 2048 + 1024 + u] = (bf16)0.f;
}

// ---------------- generic bt-GEMM: C[M,N] = A[M,K] @ B[N,K]^T ----------------
// m97 structure: 128x128 tile, BK=32, 4 waves (2x2), 64x64 per wave, 16x16x32 bf16 MFMA.
// MODE 0: bf16 C      MODE 1: bf16 C, += RT[r,c] for c<1024 (W12T build)
// MODE 2: f32 C, += aux[c] (bias)     MODE 3: logits scatter, += aux[c], mask r<3008
// MODE 4: plain f32 C
template <int MODE>
__global__ __launch_bounds__(256) void gemm_bt(
    const bf16* __restrict__ A, int lda,
    const bf16* __restrict__ B, int ldb, int K,
    void* __restrict__ C, int ldc,
    const void* __restrict__ aux) {
  __shared__ bf16 As[128 * 32];
  __shared__ bf16 Bs[128 * 32];
  const int tid = threadIdx.x;
  const int wave = tid >> 6, lane = tid & 63;
  const int wm = wave >> 1, wn = wave & 1;
  const int quad = lane >> 4, l16 = lane & 15;
  const size_t r0 = (size_t)blockIdx.y * 128;
  const size_t c0 = (size_t)blockIdx.x * 128;

  f32x4 acc[4][4] = {};

  for (int k0 = 0; k0 < K; k0 += 32) {
#pragma unroll
    for (int j = 0; j < 2; ++j) {
      int seg = j * 256 + tid;
      int row = seg >> 2, ks = seg & 3;
      async16(A + (r0 + row) * (size_t)lda + k0 + ks * 8, As + seg * 8);
    }
#pragma unroll
    for (int j = 0; j < 2; ++j) {
      int seg = j * 256 + tid;
      int row = seg >> 2, ks = seg & 3;
      async16(B + (c0 + row) * (size_t)ldb + k0 + ks * 8, Bs + seg * 8);
    }
    __syncthreads();
    bf16x8 af[4], bfr[4];
#pragma unroll
    for (int mi = 0; mi < 4; ++mi)
      af[mi] = *(const bf16x8*)(As + (wm * 64 + mi * 16 + l16) * 32 + quad * 8);
#pragma unroll
    for (int ni = 0; ni < 4; ++ni)
      bfr[ni] = *(const bf16x8*)(Bs + (wn * 64 + ni * 16 + l16) * 32 + quad * 8);
#pragma unroll
    for (int mi = 0; mi < 4; ++mi)
#pragma unroll
      for (int ni = 0; ni < 4; ++ni)
        acc[mi][ni] = __builtin_amdgcn_mfma_f32_16x16x32_bf16(af[mi], bfr[ni], acc[mi][ni], 0, 0, 0);
    __syncthreads();
  }

#pragma unroll
  for (int mi = 0; mi < 4; ++mi)
#pragma unroll
    for (int ni = 0; ni < 4; ++ni)
#pragma unroll
      for (int reg = 0; reg < 4; ++reg) {
        size_t r = r0 + wm * 64 + mi * 16 + quad * 4 + reg;
        size_t c = c0 + wn * 64 + ni * 16 + l16;
        float v = acc[mi][ni][reg];
        if (MODE == 0) {
          ((bf16*)C)[r * ldc + c] = (bf16)v;
        } else if (MODE == 1) {
          if (c < 1024) v += (float)((const bf16*)aux)[r * 1024 + c];
          ((bf16*)C)[r * ldc + c] = (bf16)v;
        } else if (MODE == 2) {
          v += ((const float*)aux)[c];
          ((float*)C)[r * ldc + c] = v;
        } else if (MODE == 3) {
          if (r < 3008) {
            size_t t = r >> 6, b = r & 63;
            ((float*)C)[(b * 47 + t) * (size_t)32000 + c] = v + ((const float*)aux)[c];
          }
        } else {
          ((float*)C)[r * ldc + c] = v;
        }
      }
}

// ---------------- persistent decoder: all 47 steps in one cooperative launch ----------------
// 128 blocks x 256 threads, 1 block/CU (LDS-bound). Block p owns z-columns
// {gate*1024 + p*8 + s : gate<4, s<8} (32 local cols). Its 32 rows of W12T live in
// LDS for the whole kernel (XOR-swizzled). Cell state c lives in 2 VGPRs/thread.
// Per step: gates GEMM (A from global, B from LDS, no k-loop barriers) -> LSTM pointwise
// -> grid.sync -> Luong attention (blocks 0..63) -> grid.sync.
// State ping-pong goes through HC itself: Sin(t) = HC(t-1), Sin(0) = S0.
__global__ __launch_bounds__(256, 1) void decoder_persistent(
    const bf16* __restrict__ S0,       // [64,2048]  (h=enc_h, ctx=0)
    const bf16* __restrict__ W12T,     // [4096,2048]
    const bf16* __restrict__ RT,       // [4096,1024] (t=0 weights)
    const float* __restrict__ precomp, // [3072,4096] x@Kx + b (t=0 row block corrected-free)
    const float* __restrict__ enc_c,   // [64,1024]
    const float* __restrict__ keys,    // [4096,1024] f32
    const bf16* __restrict__ memB,     // [4096,1024]
    bf16* __restrict__ HC)             // [3072,2048]
{
  __shared__ bf16 Bsm[32 * 2048];      // 128 KB, swizzled: byte-in-row ^= (row&7)<<4
  __shared__ float scratch[2048];      // zs (gates) / h2s+sm (attn)

  const int tid = threadIdx.x;
  const int p = blockIdx.x;            // 0..127
  const int wave = tid >> 6, lane = tid & 63;
  const int quad = lane >> 4, l16 = lane & 15;
  const int wm = wave >> 1, wn = wave & 1;
  const int n_l = wn * 16 + l16;       // local B row / z col this lane consumes
  const int bswz = (n_l & 7) << 4;
  const int growB = (n_l >> 3) * 1024 + p * 8 + (n_l & 7); // global z-col for this lane

  // ---- stage this block's 32 W12T rows into LDS once, swizzled ----
  for (int slot = tid; slot < 8192; slot += 256) {
    int nl = slot >> 8;                    // local row 0..31
    int kbs = (slot & 255) * 16;           // LDS byte-in-row
    int gkb = kbs ^ ((nl & 7) << 4);       // global byte-in-row
    int grow = (nl >> 3) * 1024 + p * 8 + (nl & 7);
    bf16x8 v = *(const bf16x8*)((const char*)W12T + (size_t)grow * 4096 + gkb);
    *(bf16x8*)((char*)Bsm + nl * 4096 + kbs) = v;
  }

  // ---- c state in registers: thread covers (b,s2) for idx = ii*256+tid ----
  float c_reg[2];
#pragma unroll
  for (int ii = 0; ii < 2; ++ii) {
    int idx = ii * 256 + tid;
    int b = idx >> 3, s2 = idx & 7;
    c_reg[ii] = enc_c[b * 1024 + p * 8 + s2];
  }

  cg::grid_group grid = cg::this_grid();
  __syncthreads();

  for (int t = 0; t < 47; ++t) {
    const bf16* Sin = (t == 0) ? S0 : (HC + (size_t)(t - 1) * 131072);
    bf16* HC_t = HC + (size_t)t * 131072;
    const float* pct = precomp + (size_t)t * 64 * 4096;

    // ---- gates GEMM: z[64, 32 local cols], K = 1024 (t=0, RT) or 2048 (W12T) ----
    f32x4 acc[2] = {};
    const bf16* a0 = Sin + (size_t)(wm * 32 + l16) * 2048 + quad * 8;
    const bf16* a1 = a0 + (size_t)16 * 2048;
    if (t == 0) {
      const bf16* brow = RT + (size_t)growB * 1024 + quad * 8;
#pragma unroll 8
      for (int ks = 0; ks < 32; ++ks) {
        bf16x8 bfr = *(const bf16x8*)(brow + ks * 32);
        bf16x8 af0 = *(const bf16x8*)(a0 + ks * 32);
        bf16x8 af1 = *(const bf16x8*)(a1 + ks * 32);
        acc[0] = __builtin_amdgcn_mfma_f32_16x16x32_bf16(af0, bfr, acc[0], 0, 0, 0);
        acc[1] = __builtin_amdgcn_mfma_f32_16x16x32_bf16(af1, bfr, acc[1], 0, 0, 0);
      }
    } else {
      const char* bbase = (const char*)Bsm + n_l * 4096;
#pragma unroll 8
      for (int ks = 0; ks < 64; ++ks) {
        bf16x8 bfr = *(const bf16x8*)(bbase + ((ks * 64 + quad * 16) ^ bswz));
        bf16x8 af0 = *(const bf16x8*)(a0 + ks * 32);
        bf16x8 af1 = *(const bf16x8*)(a1 + ks * 32);
        acc[0] = __builtin_amdgcn_mfma_f32_16x16x32_bf16(af0, bfr, acc[0], 0, 0, 0);
        acc[1] = __builtin_amdgcn_mfma_f32_16x16x32_bf16(af1, bfr, acc[1], 0, 0, 0);
      }
    }

    // ---- z + precomp -> scratch (zs layout [64 rows][32 cols]) ----
#pragma unroll
    for (int mi = 0; mi < 2; ++mi)
#pragma unroll
      for (int reg = 0; reg < 4; ++reg) {
        int row = wm * 32 + mi * 16 + quad * 4 + reg;
        scratch[row * 32 + n_l] = acc[mi][reg]
            + pct[(size_t)row * 4096 + (n_l >> 3) * 1024 + p * 8 + (n_l & 7)];
      }
    __syncthreads();

    // ---- LSTM pointwise; h -> HC_t, c stays in regs ----
#pragma unroll
    for (int ii = 0; ii < 2; ++ii) {
      int idx = ii * 256 + tid;
      int b = idx >> 3, s2 = idx & 7;
      float iv = scratch[b * 32 + s2];
      float fv = scratch[b * 32 + 8 + s2];
      float gv = scratch[b * 32 + 16 + s2];
      float ov = scratch[b * 32 + 24 + s2];
      float ig = 1.f / (1.f + __expf(-iv));
      float fg = 1.f / (1.f + __expf(-fv));
      float og = 1.f / (1.f + __expf(-ov));
      float c2 = fg * c_reg[ii] + ig * tanhf(gv);
      float h2 = og * tanhf(c2);
      c_reg[ii] = c2;
      HC_t[(size_t)b * 2048 + p * 8 + s2] = (bf16)h2;
    }
    __threadfence();
    grid.sync();
    __threadfence();

    // ---- Luong attention: blocks 0..63, one per batch ----
    if (p < 64) {
      const int b = p;
      float* h2s = scratch;            // [1024]
      float* sm = scratch + 1024;      // [64]
#pragma unroll
      for (int jj = 0; jj < 4; ++jj) {
        int u = jj * 256 + tid;
        h2s[u] = (float)HC_t[(size_t)b * 2048 + u];
      }
      __syncthreads();

      for (int ii = 0; ii < 16; ++ii) {
        int it = wave * 16 + ii;
        const float* krow = keys + ((size_t)b * 64 + it) * 1024;
        float pr = 0.f;
#pragma unroll
        for (int q = 0; q < 16; ++q) {
          int u = q * 64 + lane;
          pr += h2s[u] * krow[u];
        }
#pragma unroll
        for (int off = 32; off > 0; off >>= 1) pr += __shfl_xor(pr, off);
        if (lane == 0) sm[it] = pr;
      }
      __syncthreads();

      if (tid < 64) {
        float s = sm[tid];
        float mx = s;
#pragma unroll
        for (int off = 32; off > 0; off >>= 1) mx = fmaxf(mx, __shfl_xor(mx, off));
        float e = __expf(s - mx);
        float sum = e;
#pragma unroll
        for (int off = 32; off > 0; off >>= 1) sum += __shfl_xor(sum, off);
        sm[tid] = e / sum;
      }
      __syncthreads();

      int u0 = tid * 4;
      float a0c = 0.f, a1c = 0.f, a2c = 0.f, a3c = 0.f;
      for (int i = 0; i < 64; ++i) {
        float al = sm[i];
        bf16x4 m4 = *(const bf16x4*)(memB + ((size_t)b * 64 + i) * 1024 + u0);
        a0c += al * (float)m4[0];
        a1c += al * (float)m4[1];
        a2c += al * (float)m4[2];
        a3c += al * (float)m4[3];
      }
      HC_t[(size_t)b * 2048 + 1024 + u0 + 0] = (bf16)a0c;
      HC_t[(size_t)b * 2048 + 1024 + u0 + 1] = (bf16)a1c;
      HC_t[(size_t)b * 2048 + 1024 + u0 + 2] = (bf16)a2c;
      HC_t[(size_t)b * 2048 + 1024 + u0 + 3] = (bf16)a3c;
    }
    __threadfence();
    grid.sync();
    __threadfence();
  }
}

// ---------------- driver ----------------

extern "C" void kernel_launch(void* const* d_in, const int* in_sizes, int n_in,
                              void* d_out, int out_size, void* d_ws, size_t ws_size,
                              hipStream_t stream) {
  const int*   tokens = (const int*)d_in[0];
  const float* memory = (const float*)d_in[1];
  const float* enc_h  = (const float*)d_in[2];
  const float* enc_c  = (const float*)d_in[3];
  const float* emb    = (const float*)d_in[4];
  const float* Wm     = (const float*)d_in[5];
  const float* Wa     = (const float*)d_in[6];
  const float* lstm_k = (const float*)d_in[7];
  const float* lstm_r = (const float*)d_in[8];
  const float* lstm_b = (const float*)d_in[9];
  const float* fc_w   = (const float*)d_in[10];
  const float* fc_b   = (const float*)d_in[11];
  float* out = (float*)d_out;

  // scratch inside d_out (dead before the final logits GEMM writes out)
  char* ob = (char*)d_out;
  size_t off = 0;
  auto alloc_o = [&](size_t bytes) { char* q = ob + off; off += bytes; return q; };
  bf16*  memB    = (bf16*)alloc_o(8388608);        // [4096,1024] bf16
  float* keys    = (float*)alloc_o(16777216);      // [4096,1024] f32
  bf16*  WaB     = (bf16*)alloc_o(4194304);        // [2048,1024] bf16
  bf16*  WmT     = (bf16*)alloc_o(2097152);        // [1024,1024]
  bf16*  KpT     = (bf16*)alloc_o(8388608);        // [4096,1024]
  bf16*  KxT     = (bf16*)alloc_o(4194304);        // [4096,512]
  bf16*  RT      = (bf16*)alloc_o(8388608);        // [4096,1024]
  bf16*  WaT     = (bf16*)alloc_o(4194304);        // [1024,2048]
  bf16*  X       = (bf16*)alloc_o(3145728);        // [3072,512]
  bf16*  W12T    = (bf16*)alloc_o(16777216);       // [4096,2048]
  bf16*  S0      = (bf16*)alloc_o(262144);         // [64,2048]
  bf16*  HC      = (bf16*)alloc_o(12582912);       // [3072,2048]
  float* precomp = (float*)alloc_o(50331648);      // [3072,4096] f32

  // d_ws: only what is live during the final logits GEMM
  char* wb = (char*)d_ws;
  bf16* fcwT  = (bf16*)(wb);                       // [32000,1024] bf16 (65,536,000 B)
  bf16* attnb = (bf16*)(wb + 65536000);            // [3072,1024] bf16

  dim3 tb(32, 8);

  // precompute / converts
  cvt_bf16<<<2048, 256, 0, stream>>>(memory, memB, 4194304);
  cvt_bf16<<<2048, 256, 0, stream>>>(Wa, WaB, 2097152);
  transpose_to_bf16<<<dim3(32, 32), tb, 0, stream>>>(Wm, WmT, 1024, 1024);
  transpose_to_bf16<<<dim3(128, 32), tb, 0, stream>>>(lstm_k + (size_t)512 * 4096, KpT, 1024, 4096);
  transpose_to_bf16<<<dim3(128, 16), tb, 0, stream>>>(lstm_k, KxT, 512, 4096);
  transpose_to_bf16<<<dim3(128, 32), tb, 0, stream>>>(lstm_r, RT, 1024, 4096);
  transpose_to_bf16<<<dim3(32, 64), tb, 0, stream>>>(Wa, WaT, 2048, 1024);
  transpose_to_bf16<<<dim3(1000, 32), tb, 0, stream>>>(fc_w, fcwT, 1024, 32000);
  gather_emb<<<3072, 128, 0, stream>>>(tokens, emb, X);
  init_state<<<256, 256, 0, stream>>>(enc_h, S0);

  // keys = memory @ Wm  (f32 out)
  gemm_bt<4><<<dim3(8, 32), 256, 0, stream>>>(memB, 1024, WmT, 1024, 1024, keys, 1024, nullptr);
  // W12T[n, m] = (Wa@Kp)[m, n] + (m<1024 ? lstm_r[m, n] : 0)   (bf16 out)
  gemm_bt<1><<<dim3(16, 32), 256, 0, stream>>>(KpT, 1024, WaB, 1024, 1024, W12T, 2048, RT);
  // precomp = X @ lstm_k[0:512] + lstm_b   (f32 out)
  gemm_bt<2><<<dim3(32, 24), 256, 0, stream>>>(X, 512, KxT, 512, 512, precomp, 4096, lstm_b);

  // recurrence: single persistent cooperative kernel (47 steps, 94 grid syncs)
  {
    const bf16* S0c = S0;
    const bf16* W12Tc = W12T;
    const bf16* RTc = RT;
    const float* precompc = precomp;
    const float* enc_cc = enc_c;
    const float* keysc = keys;
    const bf16* memBc = memB;
    bf16* HCc = HC;
    void* kargs[] = { (void*)&S0c, (void*)&W12Tc, (void*)&RTc, (void*)&precompc,
                      (void*)&enc_cc, (void*)&keysc, (void*)&memBc, (void*)&HCc };
    hipLaunchCooperativeKernel((void*)decoder_persistent, dim3(128), dim3(256),
                               kargs, 0, stream);
  }

  // attn_all = HC @ Wa   (bf16 out)
  gemm_bt<0><<<dim3(8, 24), 256, 0, stream>>>(HC, 2048, WaT, 2048, 2048, attnb, 1024, nullptr);
  // logits = attn_all @ fc_w + fc_b, scattered to out[b, t, v]
  gemm_bt<3><<<dim3(250, 24), 256, 0, stream>>>(attnb, 1024, fcwT, 1024, 1024, out, 32000, fc_b);

  (void)in_sizes; (void)n_in; (void)out_size; (void)ws_size;
}

// Round 2
// 2425.217 us; speedup vs baseline: 2.6584x; 2.6584x over previous
//
#include <hip/hip_runtime.h>

typedef __bf16 bf16;
typedef __bf16 bf16x8 __attribute__((ext_vector_type(8)));
typedef __bf16 bf16x4 __attribute__((ext_vector_type(4)));
typedef float  f32x4  __attribute__((ext_vector_type(4)));

// async global->LDS, 16B per lane. LDS dest must be lane-linear within the wave.
__device__ __forceinline__ void async16(const bf16* g, bf16* l) {
  __builtin_amdgcn_global_load_lds(
      (__attribute__((address_space(1))) void*)(void*)(const_cast<bf16*>(g)),
      (__attribute__((address_space(3))) void*)(void*)l,
      16, 0, 0);
}

// ---------------- elementwise converts / transposes / gathers ----------------

__global__ void cvt_bf16(const float* __restrict__ s, bf16* __restrict__ d, int n) {
  int i = blockIdx.x * blockDim.x + threadIdx.x;
  int stride = gridDim.x * blockDim.x;
  for (int k = i; k < n; k += stride) d[k] = (bf16)s[k];
}

// dst[c, r] = src[r, c]; src is R x C f32 (row-major), dst is C x R bf16.
__global__ void transpose_to_bf16(const float* __restrict__ src, bf16* __restrict__ dst,
                                  int R, int C) {
  __shared__ float tile[32][33];
  int c0 = blockIdx.x * 32, r0 = blockIdx.y * 32;
  int tx = threadIdx.x, ty = threadIdx.y;
#pragma unroll
  for (int k = 0; k < 32; k += 8)
    tile[ty + k][tx] = src[(size_t)(r0 + ty + k) * C + (c0 + tx)];
  __syncthreads();
#pragma unroll
  for (int k = 0; k < 32; k += 8)
    dst[(size_t)(c0 + ty + k) * R + (r0 + tx)] = (bf16)tile[tx][ty + k];
}

// X[r = t*64+b, :] = bf16(emb[tokens[b,t], :]), rows >= 3008 zeroed (M padded to 3072)
__global__ void gather_emb(const int* __restrict__ tokens, const float* __restrict__ emb,
                           bf16* __restrict__ X) {
  int r = blockIdx.x;
  int tid = threadIdx.x;
  if (r < 3008) {
    int t = r >> 6, b = r & 63;
    int tok = tokens[b * 47 + t];
    const float* e = emb + (size_t)tok * 512;
    for (int k = tid; k < 512; k += 128) X[(size_t)r * 512 + k] = (bf16)e[k];
  } else {
    for (int k = tid; k < 512; k += 128) X[(size_t)r * 512 + k] = (bf16)0.f;
  }
}

// S0[b, 0:1024] = bf16(enc_h), S0[b, 1024:2048] = 0, cbuf = enc_c
__global__ void init_state(const float* __restrict__ enc_h, const float* __restrict__ enc_c,
                           bf16* __restrict__ S0, float* __restrict__ cbuf) {
  int i = blockIdx.x * 256 + threadIdx.x;   // 0..65535
  int b = i >> 10, u = i & 1023;
  S0[(size_t)b * 2048 + u]        = (bf16)enc_h[i];
  S0[(size_t)b * 2048 + 1024 + u] = (bf16)0.f;
  cbuf[i] = enc_c[i];
}

// ---------------- generic bt-GEMM: C[M,N] = A[M,K] @ B[N,K]^T ----------------
// m97 structure: 128x128 tile, BK=32, 4 waves (2x2), 64x64 per wave, 16x16x32 bf16 MFMA.
// MODE 0: bf16 C      MODE 1: bf16 C, += RT[r,c] for c<1024 (W12T build)
// MODE 2: f32 C, += aux[c] (bias)     MODE 3: logits scatter, += aux[c], mask r<3008
// MODE 4: plain f32 C
// SWAP=1: r0 from blockIdx.x, c0 from blockIdx.y (so consecutive blocks share the B panel
//         -> fixes the 12x fcwT over-fetch in the logits GEMM).
template <int MODE, int SWAP = 0>
__global__ __launch_bounds__(256) void gemm_bt(
    const bf16* __restrict__ A, int lda,
    const bf16* __restrict__ B, int ldb, int K,
    void* __restrict__ C, int ldc,
    const void* __restrict__ aux) {
  __shared__ bf16 As[128 * 32];
  __shared__ bf16 Bs[128 * 32];
  const int tid = threadIdx.x;
  const int wave = tid >> 6, lane = tid & 63;
  const int wm = wave >> 1, wn = wave & 1;
  const int quad = lane >> 4, l16 = lane & 15;
  const size_t r0 = (size_t)(SWAP ? blockIdx.x : blockIdx.y) * 128;
  const size_t c0 = (size_t)(SWAP ? blockIdx.y : blockIdx.x) * 128;

  f32x4 acc[4][4] = {};

  for (int k0 = 0; k0 < K; k0 += 32) {
#pragma unroll
    for (int j = 0; j < 2; ++j) {
      int seg = j * 256 + tid;
      int row = seg >> 2, ks = seg & 3;
      async16(A + (r0 + row) * (size_t)lda + k0 + ks * 8, As + seg * 8);
    }
#pragma unroll
    for (int j = 0; j < 2; ++j) {
      int seg = j * 256 + tid;
      int row = seg >> 2, ks = seg & 3;
      async16(B + (c0 + row) * (size_t)ldb + k0 + ks * 8, Bs + seg * 8);
    }
    __syncthreads();
    bf16x8 af[4], bfr[4];
#pragma unroll
    for (int mi = 0; mi < 4; ++mi)
      af[mi] = *(const bf16x8*)(As + (wm * 64 + mi * 16 + l16) * 32 + quad * 8);
#pragma unroll
    for (int ni = 0; ni < 4; ++ni)
      bfr[ni] = *(const bf16x8*)(Bs + (wn * 64 + ni * 16 + l16) * 32 + quad * 8);
#pragma unroll
    for (int mi = 0; mi < 4; ++mi)
#pragma unroll
      for (int ni = 0; ni < 4; ++ni)
        acc[mi][ni] = __builtin_amdgcn_mfma_f32_16x16x32_bf16(af[mi], bfr[ni], acc[mi][ni], 0, 0, 0);
    __syncthreads();
  }

#pragma unroll
  for (int mi = 0; mi < 4; ++mi)
#pragma unroll
    for (int ni = 0; ni < 4; ++ni)
#pragma unroll
      for (int reg = 0; reg < 4; ++reg) {
        size_t r = r0 + wm * 64 + mi * 16 + quad * 4 + reg;
        size_t c = c0 + wn * 64 + ni * 16 + l16;
        float v = acc[mi][ni][reg];
        if (MODE == 0) {
          ((bf16*)C)[r * ldc + c] = (bf16)v;
        } else if (MODE == 1) {
          if (c < 1024) v += (float)((const bf16*)aux)[r * 1024 + c];
          ((bf16*)C)[r * ldc + c] = (bf16)v;
        } else if (MODE == 2) {
          v += ((const float*)aux)[c];
          ((float*)C)[r * ldc + c] = v;
        } else if (MODE == 3) {
          if (r < 3008) {
            size_t t = r >> 6, b = r & 63;
            ((float*)C)[(b * 47 + t) * (size_t)32000 + c] = v + ((const float*)aux)[c];
          }
        } else {
          ((float*)C)[r * ldc + c] = v;
        }
      }
}

// ---------------- per-step kernel A: z-GEMM + LSTM gates (fused) ----------------
// 256 blocks x 256 threads (all CUs). Block p owns hidden cols [p*4, p*4+4) across all
// 4 gates -> 16 z-columns. Its 16-row weight panel (64 KB) is staged to LDS in ONE shot
// (single vmcnt drain, vs 64 round-trips before), XOR-swizzled via pre-swizzled global
// source so the 16-row ds_read_b128 column read is ~2-way conflict (free).
// A-fragments are read straight from L2-resident Sin (256 KB) -> barrier-free K-loop.
// Block p touches the SAME weight panel every step -> warm in its XCD's L2 across steps.
template <int KK>
__global__ __launch_bounds__(256) void step_gates2(
    const bf16* __restrict__ Sin,      // [64, 2048]  (h, ctx) rows
    const bf16* __restrict__ Bt,       // RT [4096,1024] (t=0) or W12T [4096,2048]
    int ldb,
    const float* __restrict__ pct,     // precomp + t*64*4096
    float* __restrict__ cbuf,          // [64, 1024]
    bf16* __restrict__ HC_t)           // [64, 2048] (h2 part written)
{
  __shared__ bf16 Bs[16 * 2048];       // 64 KB
  __shared__ float zs[64 * 16];        // 4 KB
  const int tid = threadIdx.x;
  const int p = blockIdx.x;            // 0..255
  const int wave = tid >> 6, lane = tid & 63;
  const int quad = lane >> 4, l16 = lane & 15;

  // ---- stage whole B panel, swizzled: LDS[n][kb] = G[n][kb ^ ((n&7)<<4)] ----
  constexpr int NSEG = KK / 8;                    // 16B segments per row
  constexpr int SH = (KK == 2048) ? 8 : 7;        // log2(NSEG)
#pragma unroll
  for (int i = 0; i < 16 * NSEG / 256; ++i) {
    int seg = i * 256 + tid;
    int n = seg >> SH;                 // wave-uniform (64 | NSEG)
    int ko = seg & (NSEG - 1);
    int gkb = (ko * 16) ^ ((n & 7) << 4);
    int ng = (n >> 2) * 1024 + p * 4 + (n & 3);
    async16(Bt + (size_t)ng * ldb + (gkb >> 1), Bs + n * 2048 + ko * 8);
  }

  const bf16* arow = Sin + (size_t)(wave * 16 + l16) * 2048 + quad * 8;
  const char* bbase = (const char*)Bs + l16 * 4096;
  const int bswz = (l16 & 7) << 4;
  __syncthreads();                     // single vmcnt(0) drain + barrier

  // ---- barrier-free K-loop; 2 accumulators break the MFMA dependence chain ----
  f32x4 acc0 = {}, acc1 = {};
  constexpr int KS = KK / 32;
#pragma unroll 8
  for (int ks = 0; ks < KS; ks += 2) {
    bf16x8 b0 = *(const bf16x8*)(bbase + ((ks * 64 + quad * 16) ^ bswz));
    bf16x8 a0 = *(const bf16x8*)(arow + (size_t)ks * 32);
    acc0 = __builtin_amdgcn_mfma_f32_16x16x32_bf16(a0, b0, acc0, 0, 0, 0);
    bf16x8 b1 = *(const bf16x8*)(bbase + (((ks + 1) * 64 + quad * 16) ^ bswz));
    bf16x8 a1 = *(const bf16x8*)(arow + (size_t)(ks + 1) * 32);
    acc1 = __builtin_amdgcn_mfma_f32_16x16x32_bf16(a1, b1, acc1, 0, 0, 0);
  }

  // ---- z + precomp -> zs[row][n_local] ----
  {
    int gcol = (l16 >> 2) * 1024 + p * 4 + (l16 & 3);
#pragma unroll
    for (int reg = 0; reg < 4; ++reg) {
      int row = wave * 16 + quad * 4 + reg;
      zs[row * 16 + l16] = acc0[reg] + acc1[reg] + pct[(size_t)row * 4096 + gcol];
    }
  }
  __syncthreads();

  // ---- LSTM pointwise: one (b, s) value per thread ----
  {
    int b = tid >> 2, s = tid & 3;
    int j = p * 4 + s;
    float iv = zs[b * 16 + s];
    float fv = zs[b * 16 + 4 + s];
    float gv = zs[b * 16 + 8 + s];
    float ov = zs[b * 16 + 12 + s];
    float c_old = cbuf[b * 1024 + j];
    float ig = 1.f / (1.f + __expf(-iv));
    float fg = 1.f / (1.f + __expf(-fv));
    float og = 1.f / (1.f + __expf(-ov));
    float c2 = fg * c_old + ig * tanhf(gv);
    float h2 = og * tanhf(c2);
    cbuf[b * 1024 + j] = c2;
    HC_t[(size_t)b * 2048 + j] = (bf16)h2;
  }
}

// ---------------- per-step kernel B: Luong attention ----------------
// One block per batch b. Vectorized: each lane holds h2[lane*16..+16) in regs;
// score rows read as 4x f32x4; ctx loop unchanged but single store target (HC).
__global__ __launch_bounds__(256) void step_attn2(
    bf16* __restrict__ HC_t,           // h2 read at [b*2048..+1024), ctx written at +1024
    const float* __restrict__ keys,    // [4096, 1024] f32
    const bf16* __restrict__ memB)     // [4096, 1024] bf16
{
  __shared__ float sm[64];
  const int b = blockIdx.x;
  const int tid = threadIdx.x;
  const int wave = tid >> 6, lane = tid & 63;

  float hv[16];
  {
    const bf16* hp = HC_t + (size_t)b * 2048 + lane * 16;
    bf16x8 h0 = *(const bf16x8*)(hp);
    bf16x8 h1 = *(const bf16x8*)(hp + 8);
#pragma unroll
    for (int e = 0; e < 8; ++e) { hv[e] = (float)h0[e]; hv[8 + e] = (float)h1[e]; }
  }

#pragma unroll 4
  for (int ii = 0; ii < 16; ++ii) {
    int it = wave * 16 + ii;
    const float* krow = keys + ((size_t)b * 64 + it) * 1024 + lane * 16;
    f32x4 k0 = *(const f32x4*)(krow);
    f32x4 k1 = *(const f32x4*)(krow + 4);
    f32x4 k2 = *(const f32x4*)(krow + 8);
    f32x4 k3 = *(const f32x4*)(krow + 12);
    float pr = hv[0] * k0[0] + hv[1] * k0[1] + hv[2] * k0[2] + hv[3] * k0[3]
             + hv[4] * k1[0] + hv[5] * k1[1] + hv[6] * k1[2] + hv[7] * k1[3]
             + hv[8] * k2[0] + hv[9] * k2[1] + hv[10] * k2[2] + hv[11] * k2[3]
             + hv[12] * k3[0] + hv[13] * k3[1] + hv[14] * k3[2] + hv[15] * k3[3];
#pragma unroll
    for (int off = 32; off > 0; off >>= 1) pr += __shfl_xor(pr, off);
    if (lane == 0) sm[it] = pr;
  }
  __syncthreads();

  if (tid < 64) {
    float s = sm[tid];
    float mx = s;
#pragma unroll
    for (int off = 32; off > 0; off >>= 1) mx = fmaxf(mx, __shfl_xor(mx, off));
    float e = __expf(s - mx);
    float sum = e;
#pragma unroll
    for (int off = 32; off > 0; off >>= 1) sum += __shfl_xor(sum, off);
    sm[tid] = e / sum;
  }
  __syncthreads();

  int u0 = tid * 4;
  float a0 = 0.f, a1 = 0.f, a2 = 0.f, a3 = 0.f;
#pragma unroll 4
  for (int i = 0; i < 64; ++i) {
    float al = sm[i];
    bf16x4 m4 = *(const bf16x4*)(memB + ((size_t)b * 64 + i) * 1024 + u0);
    a0 += al * (float)m4[0];
    a1 += al * (float)m4[1];
    a2 += al * (float)m4[2];
    a3 += al * (float)m4[3];
  }
  bf16* so = HC_t + (size_t)b * 2048 + 1024 + u0;
  so[0] = (bf16)a0;
  so[1] = (bf16)a1;
  so[2] = (bf16)a2;
  so[3] = (bf16)a3;
}

// ---------------- driver ----------------

extern "C" void kernel_launch(void* const* d_in, const int* in_sizes, int n_in,
                              void* d_out, int out_size, void* d_ws, size_t ws_size,
                              hipStream_t stream) {
  const int*   tokens = (const int*)d_in[0];
  const float* memory = (const float*)d_in[1];
  const float* enc_h  = (const float*)d_in[2];
  const float* enc_c  = (const float*)d_in[3];
  const float* emb    = (const float*)d_in[4];
  const float* Wm     = (const float*)d_in[5];
  const float* Wa     = (const float*)d_in[6];
  const float* lstm_k = (const float*)d_in[7];
  const float* lstm_r = (const float*)d_in[8];
  const float* lstm_b = (const float*)d_in[9];
  const float* fc_w   = (const float*)d_in[10];
  const float* fc_b   = (const float*)d_in[11];
  float* out = (float*)d_out;

  // scratch inside d_out (dead before the final logits GEMM writes out)
  char* ob = (char*)d_out;
  size_t off = 0;
  auto alloc_o = [&](size_t bytes) { char* q = ob + off; off += bytes; return q; };
  bf16*  memB    = (bf16*)alloc_o(8388608);        // [4096,1024] bf16
  float* keys    = (float*)alloc_o(16777216);      // [4096,1024] f32
  bf16*  WaB     = (bf16*)alloc_o(4194304);        // [2048,1024] bf16
  bf16*  WmT     = (bf16*)alloc_o(2097152);        // [1024,1024]
  bf16*  KpT     = (bf16*)alloc_o(8388608);        // [4096,1024]
  bf16*  KxT     = (bf16*)alloc_o(4194304);        // [4096,512]
  bf16*  RT      = (bf16*)alloc_o(8388608);        // [4096,1024]
  bf16*  WaT     = (bf16*)alloc_o(4194304);        // [1024,2048]
  bf16*  X       = (bf16*)alloc_o(3145728);        // [3072,512]
  bf16*  W12T    = (bf16*)alloc_o(16777216);       // [4096,2048]
  bf16*  S0      = (bf16*)alloc_o(262144);         // [64,2048]
  float* cbuf    = (float*)alloc_o(262144);        // [64,1024]
  bf16*  HC      = (bf16*)alloc_o(12582912);       // [3072,2048]
  float* precomp = (float*)alloc_o(50331648);      // [3072,4096] f32

  // d_ws: only what is live during the final logits GEMM
  char* wb = (char*)d_ws;
  bf16* fcwT  = (bf16*)(wb);                       // [32000,1024] bf16 (65,536,000 B)
  bf16* attnb = (bf16*)(wb + 65536000);            // [3072,1024] bf16

  dim3 tb(32, 8);

  // precompute / converts
  cvt_bf16<<<2048, 256, 0, stream>>>(memory, memB, 4194304);
  cvt_bf16<<<2048, 256, 0, stream>>>(Wa, WaB, 2097152);
  transpose_to_bf16<<<dim3(32, 32), tb, 0, stream>>>(Wm, WmT, 1024, 1024);
  transpose_to_bf16<<<dim3(128, 32), tb, 0, stream>>>(lstm_k + (size_t)512 * 4096, KpT, 1024, 4096);
  transpose_to_bf16<<<dim3(128, 16), tb, 0, stream>>>(lstm_k, KxT, 512, 4096);
  transpose_to_bf16<<<dim3(128, 32), tb, 0, stream>>>(lstm_r, RT, 1024, 4096);
  transpose_to_bf16<<<dim3(32, 64), tb, 0, stream>>>(Wa, WaT, 2048, 1024);
  transpose_to_bf16<<<dim3(1000, 32), tb, 0, stream>>>(fc_w, fcwT, 1024, 32000);
  gather_emb<<<3072, 128, 0, stream>>>(tokens, emb, X);
  init_state<<<256, 256, 0, stream>>>(enc_h, enc_c, S0, cbuf);

  // keys = memory @ Wm  (f32 out)
  gemm_bt<4><<<dim3(8, 32), 256, 0, stream>>>(memB, 1024, WmT, 1024, 1024, keys, 1024, nullptr);
  // W12T[n, m] = (Wa@Kp)[m, n] + (m<1024 ? lstm_r[m, n] : 0)   (bf16 out)
  gemm_bt<1><<<dim3(16, 32), 256, 0, stream>>>(KpT, 1024, WaB, 1024, 1024, W12T, 2048, RT);
  // precomp = X @ lstm_k[0:512] + lstm_b   (f32 out)
  gemm_bt<2><<<dim3(32, 24), 256, 0, stream>>>(X, 512, KxT, 512, 512, precomp, 4096, lstm_b);

  // recurrence: 2 kernels per step; state flows through HC (Sin(t) = HC(t-1))
  for (int t = 0; t < 47; ++t) {
    const bf16* Sin = (t == 0) ? S0 : (HC + (size_t)(t - 1) * 131072);
    bf16* HC_t = HC + (size_t)t * 131072;
    const float* pct = precomp + (size_t)t * 262144;
    if (t == 0)
      step_gates2<1024><<<256, 256, 0, stream>>>(Sin, RT, 1024, pct, cbuf, HC_t);
    else
      step_gates2<2048><<<256, 256, 0, stream>>>(Sin, W12T, 2048, pct, cbuf, HC_t);
    step_attn2<<<64, 256, 0, stream>>>(HC_t, keys, memB);
  }

  // attn_all = HC @ Wa   (bf16 out)
  gemm_bt<0><<<dim3(8, 24), 256, 0, stream>>>(HC, 2048, WaT, 2048, 2048, attnb, 1024, nullptr);
  // logits = attn_all @ fc_w + fc_b, scattered to out[b, t, v]
  // SWAP grid: consecutive blocks share one 256 KB fcwT panel -> FETCH ~824 MB -> ~150 MB
  gemm_bt<3, 1><<<dim3(24, 250), 256, 0, stream>>>(attnb, 1024, fcwT, 1024, 1024, out, 32000, fc_b);

  (void)in_sizes; (void)n_in; (void)out_size; (void)ws_size;
}